// Round 1
// baseline (359.085 us; speedup 1.0000x reference)
//
#include <hip/hip_runtime.h>
#include <hip/hip_fp16.h>

constexpr int N_ = 300;
constexpr int R_ = 48;
constexpr int B_ = 1048576;
constexpr size_t MT_ELEMS = (size_t)3 * N_ * N_ * R_;   // 12,960,000 fp16 elems

// --- Kernel 1a: collapse the "vector" (line) bilinear sample analytically ---
// For img (R, N, 1), y=0, x=c:  out = 0.5*(V[149]+V[150]) * (1 - |c|/2).
// Precompute vsum[i*48+r] = 0.5*(V[i,r,149] + V[i,r,150]).
__global__ __launch_bounds__(256) void k_prep_vsum(const float* __restrict__ vec,
                                                   float* __restrict__ vsum) {
    int t = blockIdx.x * 256 + threadIdx.x;
    if (t < 3 * R_) vsum[t] = 0.5f * (vec[t * N_ + 149] + vec[t * N_ + 150]);
}

// --- Kernel 1b: transpose matrices (3,R,N,N) f32 -> (3,N,N,R) fp16 in ws ---
// One block per (plane, y-row). Coalesced f32 reads -> LDS -> coalesced
// __half2 writes. LDS stride N_+1 breaks bank conflicts on the r-major read.
__global__ __launch_bounds__(256) void k_transpose(const float* __restrict__ mat,
                                                   __half2* __restrict__ mt2) {
    __shared__ float tile[R_][N_ + 1];
    int i = blockIdx.x / N_;
    int y = blockIdx.x - i * N_;
    const float* src = mat + ((size_t)i * R_ * N_ + y) * N_;   // + r*N*N + x
    for (int idx = threadIdx.x; idx < R_ * N_; idx += 256) {
        int r = idx / N_;
        int x = idx - r * N_;
        tile[r][x] = src[(size_t)r * N_ * N_ + x];
    }
    __syncthreads();
    __half2* dst = mt2 + (size_t)(i * N_ + y) * N_ * (R_ / 2);
    for (int idx = threadIdx.x; idx < N_ * (R_ / 2); idx += 256) {
        int x  = idx / (R_ / 2);
        int jj = idx - x * (R_ / 2);
        dst[idx] = __floats2half2_rn(tile[2 * jj][x], tile[2 * jj + 1][x]);
    }
}

// --- Kernel 2: main gather. thread = (b, channel-quad j in [0,12)) ---
union H4 { float2 f2; __half2 h2[2]; };

__global__ __launch_bounds__(256) void k_gather(const float* __restrict__ coords,
                                                const __half* __restrict__ M,
                                                const float* __restrict__ vsum,
                                                float* __restrict__ out) {
    int t = blockIdx.x * 256 + threadIdx.x;
    int b = t / 12;
    int j = t - b * 12;
    if (b >= B_) return;

    const float c0 = coords[b * 3 + 0];
    const float c1 = coords[b * 3 + 1];
    const float c2 = coords[b * 3 + 2];
    const float xs[3] = {c1, c2, c0};
    const float ys[3] = {c2, c0, c1};
    const float cs[3] = {c0, c1, c2};

    const float4* vs4 = reinterpret_cast<const float4*>(vsum);
    float* outp = out + (size_t)b * 144 + 4 * j;

#pragma unroll
    for (int i = 0; i < 3; ++i) {
        float ix = (xs[i] + 1.0f) * 150.0f - 0.5f;
        float iy = (ys[i] + 1.0f) * 150.0f - 0.5f;
        float ix0f = floorf(ix), iy0f = floorf(iy);
        float wx = ix - ix0f, wy = iy - iy0f;
        int ix0 = (int)ix0f, iy0 = (int)iy0f;
        int ix1 = ix0 + 1,   iy1 = iy0 + 1;

        float w00 = (1.0f - wy) * (1.0f - wx);
        float w01 = (1.0f - wy) * wx;
        float w10 = wy * (1.0f - wx);
        float w11 = wy * wx;

        bool bx0 = (unsigned)ix0 < (unsigned)N_;
        bool bx1 = (unsigned)ix1 < (unsigned)N_;
        bool by0 = (unsigned)iy0 < (unsigned)N_;
        bool by1 = (unsigned)iy1 < (unsigned)N_;
        if (!(bx0 && by0)) w00 = 0.0f;
        if (!(bx1 && by0)) w01 = 0.0f;
        if (!(bx0 && by1)) w10 = 0.0f;
        if (!(bx1 && by1)) w11 = 0.0f;

        int cx0 = min(max(ix0, 0), N_ - 1), cx1 = min(max(ix1, 0), N_ - 1);
        int cy0 = min(max(iy0, 0), N_ - 1), cy1 = min(max(iy1, 0), N_ - 1);

        const __half* Mi = M + (size_t)i * N_ * N_ * R_;
        int o00 = (cy0 * N_ + cx0) * R_ + 4 * j;
        int o01 = (cy0 * N_ + cx1) * R_ + 4 * j;
        int o10 = (cy1 * N_ + cx0) * R_ + 4 * j;
        int o11 = (cy1 * N_ + cx1) * R_ + 4 * j;

        H4 u00, u01, u10, u11;
        u00.f2 = *reinterpret_cast<const float2*>(Mi + o00);
        u01.f2 = *reinterpret_cast<const float2*>(Mi + o01);
        u10.f2 = *reinterpret_cast<const float2*>(Mi + o10);
        u11.f2 = *reinterpret_cast<const float2*>(Mi + o11);

        float2 a00 = __half22float2(u00.h2[0]), b00 = __half22float2(u00.h2[1]);
        float2 a01 = __half22float2(u01.h2[0]), b01 = __half22float2(u01.h2[1]);
        float2 a10 = __half22float2(u10.h2[0]), b10 = __half22float2(u10.h2[1]);
        float2 a11 = __half22float2(u11.h2[0]), b11 = __half22float2(u11.h2[1]);

        float vw = 1.0f - 0.5f * fabsf(cs[i]);
        float4 vv = vs4[i * 12 + j];

        float4 r4;
        r4.x = fmaf(a00.x, w00, fmaf(a01.x, w01, fmaf(a10.x, w10, a11.x * w11))) * (vv.x * vw);
        r4.y = fmaf(a00.y, w00, fmaf(a01.y, w01, fmaf(a10.y, w10, a11.y * w11))) * (vv.y * vw);
        r4.z = fmaf(b00.x, w00, fmaf(b01.x, w01, fmaf(b10.x, w10, b11.x * w11))) * (vv.z * vw);
        r4.w = fmaf(b00.y, w00, fmaf(b01.y, w01, fmaf(b10.y, w10, b11.y * w11))) * (vv.w * vw);

        *reinterpret_cast<float4*>(outp + i * 48) = r4;
    }
}

extern "C" void kernel_launch(void* const* d_in, const int* in_sizes, int n_in,
                              void* d_out, int out_size, void* d_ws, size_t ws_size,
                              hipStream_t stream) {
    const float* coords   = (const float*)d_in[0];
    const float* matrices = (const float*)d_in[1];
    const float* vectors  = (const float*)d_in[2];
    float* out = (float*)d_out;

    __half* mt   = (__half*)d_ws;
    float*  vsum = (float*)((char*)d_ws + MT_ELEMS * sizeof(__half));  // 25,920,000 B offset

    hipLaunchKernelGGL(k_prep_vsum, dim3(1), dim3(256), 0, stream, vectors, vsum);
    hipLaunchKernelGGL(k_transpose, dim3(3 * N_), dim3(256), 0, stream, matrices, (__half2*)mt);

    const int total = B_ * 12;
    hipLaunchKernelGGL(k_gather, dim3(total / 256), dim3(256), 0, stream,
                       coords, mt, vsum, out);
}

// Round 3
// 329.655 us; speedup vs baseline: 1.0893x; 1.0893x over previous
//
#include <hip/hip_runtime.h>
#include <hip/hip_fp16.h>

constexpr int N_ = 300;
constexpr int R_ = 48;
constexpr int B_ = 1048576;
constexpr size_t MT_ELEMS = (size_t)3 * N_ * N_ * R_;   // 12,960,000 fp16 elems

typedef float f32x4 __attribute__((ext_vector_type(4)));

// --- Kernel 1a: collapse the "vector" (line) bilinear sample analytically ---
// For img (R, N, 1), y=0, x=c:  out = 0.5*(V[149]+V[150]) * (1 - |c|/2).
__global__ __launch_bounds__(256) void k_prep_vsum(const float* __restrict__ vec,
                                                   float* __restrict__ vsum) {
    int t = blockIdx.x * 256 + threadIdx.x;
    if (t < 3 * R_) vsum[t] = 0.5f * (vec[t * N_ + 149] + vec[t * N_ + 150]);
}

// --- Kernel 1b: transpose matrices (3,R,N,N) f32 -> (3,N,N,R) fp16 in ws ---
__global__ __launch_bounds__(256) void k_transpose(const float* __restrict__ mat,
                                                   __half2* __restrict__ mt2) {
    __shared__ float tile[R_][N_ + 1];
    int i = blockIdx.x / N_;
    int y = blockIdx.x - i * N_;
    const float* src = mat + ((size_t)i * R_ * N_ + y) * N_;   // + r*N*N + x
    for (int idx = threadIdx.x; idx < R_ * N_; idx += 256) {
        int r = idx / N_;
        int x = idx - r * N_;
        tile[r][x] = src[(size_t)r * N_ * N_ + x];
    }
    __syncthreads();
    __half2* dst = mt2 + (size_t)(i * N_ + y) * N_ * (R_ / 2);
    for (int idx = threadIdx.x; idx < N_ * (R_ / 2); idx += 256) {
        int x  = idx / (R_ / 2);
        int jj = idx - x * (R_ / 2);
        dst[idx] = __floats2half2_rn(tile[2 * jj][x], tile[2 * jj + 1][x]);
    }
}

// --- Kernel 2: plane-partitioned gather. Each XCD group owns ONE plane so its
// L2 working set is 8.64 MB (one plane's fp16 texture) instead of 26 MB.
// blockIdx.x % 8 == XCD on MI355X (round-robin dispatch).
// Thread = (b, j in [0,6)): 8 channels per lane, 16B gathered loads.
union H8 { float4 f4; __half2 h2[4]; };

__global__ __launch_bounds__(256) void k_gather(const float* __restrict__ coords,
                                                const __half* __restrict__ M,
                                                const float* __restrict__ vsum,
                                                float* __restrict__ out) {
    int bid  = blockIdx.x;
    int xcd  = bid & 7;
    int sidx = bid >> 3;

    int plane, slot, perXcd;
    if (xcd < 3)      { plane = 0; slot = xcd;     perXcd = 8192;  }
    else if (xcd < 6) { plane = 1; slot = xcd - 3; perXcd = 8192;  }
    else              { plane = 2; slot = xcd - 6; perXcd = 12288; }
    if (sidx >= perXcd) return;

    int g = (slot * perXcd + sidx) * 256 + threadIdx.x;   // [0, 6*B)
    int b = g / 6;
    int j = g - b * 6;

    const float c0 = coords[b * 3 + 0];
    const float c1 = coords[b * 3 + 1];
    const float c2 = coords[b * 3 + 2];
    float xc, yc, cc;
    if (plane == 0)      { xc = c1; yc = c2; cc = c0; }
    else if (plane == 1) { xc = c2; yc = c0; cc = c1; }
    else                 { xc = c0; yc = c1; cc = c2; }

    float ix = (xc + 1.0f) * 150.0f - 0.5f;
    float iy = (yc + 1.0f) * 150.0f - 0.5f;
    float ix0f = floorf(ix), iy0f = floorf(iy);
    float wx = ix - ix0f, wy = iy - iy0f;
    int ix0 = (int)ix0f, iy0 = (int)iy0f;
    int ix1 = ix0 + 1,   iy1 = iy0 + 1;

    float w00 = (1.0f - wy) * (1.0f - wx);
    float w01 = (1.0f - wy) * wx;
    float w10 = wy * (1.0f - wx);
    float w11 = wy * wx;

    bool bx0 = (unsigned)ix0 < (unsigned)N_;
    bool bx1 = (unsigned)ix1 < (unsigned)N_;
    bool by0 = (unsigned)iy0 < (unsigned)N_;
    bool by1 = (unsigned)iy1 < (unsigned)N_;
    if (!(bx0 && by0)) w00 = 0.0f;
    if (!(bx1 && by0)) w01 = 0.0f;
    if (!(bx0 && by1)) w10 = 0.0f;
    if (!(bx1 && by1)) w11 = 0.0f;

    int cx0 = min(max(ix0, 0), N_ - 1), cx1 = min(max(ix1, 0), N_ - 1);
    int cy0 = min(max(iy0, 0), N_ - 1), cy1 = min(max(iy1, 0), N_ - 1);

    const __half* Mi = M + (size_t)plane * N_ * N_ * R_;
    int o00 = (cy0 * N_ + cx0) * R_ + 8 * j;
    int o01 = (cy0 * N_ + cx1) * R_ + 8 * j;
    int o10 = (cy1 * N_ + cx0) * R_ + 8 * j;
    int o11 = (cy1 * N_ + cx1) * R_ + 8 * j;

    H8 u00, u01, u10, u11;
    u00.f4 = *reinterpret_cast<const float4*>(Mi + o00);
    u01.f4 = *reinterpret_cast<const float4*>(Mi + o01);
    u10.f4 = *reinterpret_cast<const float4*>(Mi + o10);
    u11.f4 = *reinterpret_cast<const float4*>(Mi + o11);

    float vw = 1.0f - 0.5f * fabsf(cc);
    const float4* vs4 = reinterpret_cast<const float4*>(vsum + plane * R_ + 8 * j);
    float4 vv0 = vs4[0];
    float4 vv1 = vs4[1];

    float r[8];
#pragma unroll
    for (int k = 0; k < 4; ++k) {
        float2 a00 = __half22float2(u00.h2[k]);
        float2 a01 = __half22float2(u01.h2[k]);
        float2 a10 = __half22float2(u10.h2[k]);
        float2 a11 = __half22float2(u11.h2[k]);
        r[2 * k]     = fmaf(a00.x, w00, fmaf(a01.x, w01, fmaf(a10.x, w10, a11.x * w11)));
        r[2 * k + 1] = fmaf(a00.y, w00, fmaf(a01.y, w01, fmaf(a10.y, w10, a11.y * w11)));
    }

    f32x4 s0, s1;
    s0.x = r[0] * (vv0.x * vw); s0.y = r[1] * (vv0.y * vw);
    s0.z = r[2] * (vv0.z * vw); s0.w = r[3] * (vv0.w * vw);
    s1.x = r[4] * (vv1.x * vw); s1.y = r[5] * (vv1.y * vw);
    s1.z = r[6] * (vv1.z * vw); s1.w = r[7] * (vv1.w * vw);

    float* outp = out + (size_t)b * 144 + plane * 48 + 8 * j;
    __builtin_nontemporal_store(s0, reinterpret_cast<f32x4*>(outp));
    __builtin_nontemporal_store(s1, reinterpret_cast<f32x4*>(outp) + 1);
}

extern "C" void kernel_launch(void* const* d_in, const int* in_sizes, int n_in,
                              void* d_out, int out_size, void* d_ws, size_t ws_size,
                              hipStream_t stream) {
    const float* coords   = (const float*)d_in[0];
    const float* matrices = (const float*)d_in[1];
    const float* vectors  = (const float*)d_in[2];
    float* out = (float*)d_out;

    __half* mt   = (__half*)d_ws;
    float*  vsum = (float*)((char*)d_ws + MT_ELEMS * sizeof(__half));

    hipLaunchKernelGGL(k_prep_vsum, dim3(1), dim3(256), 0, stream, vectors, vsum);
    hipLaunchKernelGGL(k_transpose, dim3(3 * N_), dim3(256), 0, stream, matrices, (__half2*)mt);

    // 8 XCD streams x 12288 blocks (XCDs 0-5 only use 8192 of them).
    hipLaunchKernelGGL(k_gather, dim3(8 * 12288), dim3(256), 0, stream,
                       coords, mt, vsum, out);
}